// Round 1
// baseline (57.763 us; speedup 1.0000x reference)
//
#include <hip/hip_runtime.h>

// AdderConvReLUBlock: reference computes relu(0 - sum_{ci,ky,kx} |patch - w|).
// The accumulator is a negated sum of absolute values, hence <= 0 everywhere;
// relu() of it is identically 0.0 unless a full 3x3x32 patch exactly equals a
// weight slice (measure-zero for random normal inputs). The whole adder-conv
// is dead code behind the ReLU -> the optimal kernel is a zero-fill of d_out.
// Harness poisons d_out with 0xAA before every timed launch, so we must write
// the full 8 MiB each call.
//
// Floor arithmetic: 8 MiB write-only, fits in aggregate L2 (32 MiB) -> store
// ceiling ~0.25-1.3 us. Prior measured 58 us implies fixed overhead dominates;
// this round's rocprof capture (dispatch dur_us vs total) arbitrates that.

__global__ __launch_bounds__(256)
void AdderConvReLUBlock_zero_kernel(float4* __restrict__ out, int n4) {
    int i = blockIdx.x * blockDim.x + threadIdx.x;
    int stride = gridDim.x * blockDim.x;
    for (; i < n4; i += stride) {
        out[i] = make_float4(0.0f, 0.0f, 0.0f, 0.0f);
    }
}

extern "C" void kernel_launch(void* const* d_in, const int* in_sizes, int n_in,
                              void* d_out, int out_size, void* d_ws, size_t ws_size,
                              hipStream_t stream) {
    (void)d_in; (void)in_sizes; (void)n_in; (void)d_ws; (void)ws_size;
    // out_size = 4*32*128*128 = 2,097,152 floats, divisible by 4.
    int n4 = out_size / 4;
    int block = 256;
    int grid = (n4 + block - 1) / block;  // 2048 blocks = 8/CU, one float4/thread
    if (grid > 2048) grid = 2048;         // grid-stride handles any overflow
    AdderConvReLUBlock_zero_kernel<<<grid, block, 0, stream>>>((float4*)d_out, n4);
}